// Round 1
// baseline (632.311 us; speedup 1.0000x reference)
//
#include <hip/hip_runtime.h>
#include <hip/hip_bf16.h>

#define KREM 172
#define NDIM 11008        // 172 * 64
#define JPAD 176          // 11 * 16
#define KP_HAD 192        // padded K for hadB (6 * 32)
#define KP_Y 256          // padded K stride for swizzled Y^T in LDS

typedef __bf16 bf16x8 __attribute__((ext_vector_type(8)));
typedef float  f32x4  __attribute__((ext_vector_type(4)));

__device__ __forceinline__ unsigned short f2bf(float f) {
  union { float f; unsigned int u; } c; c.f = f;
  unsigned int u = c.u;
  u += 0x7fffu + ((u >> 16) & 1u);   // round-to-nearest-even
  return (unsigned short)(u >> 16);
}

// Convert had (172x172 fp32) -> hadB (176x192 bf16, zero padded), row-major.
__global__ void prep_had_kernel(const float* __restrict__ had,
                                unsigned short* __restrict__ hadB) {
  int idx = blockIdx.x * 256 + threadIdx.x;
  if (idx >= JPAD * KP_HAD) return;
  int j = idx / KP_HAD;
  int k = idx - j * KP_HAD;
  float v = (j < KREM && k < KREM) ? had[j * KREM + k] : 0.0f;
  hadB[idx] = f2bf(v);
}

__global__ void __launch_bounds__(256, 4) had_fused_kernel(
    const float* __restrict__ x, const unsigned short* __restrict__ hadB,
    float* __restrict__ out) {
  // Swizzled Y^T: element (n,k) at Yt[n*KP_Y + ((k>>3)^(n>>3))*8 + (k&7)], 32 KB
  __shared__ unsigned short Yt[64 * KP_Y];

  const int tid  = threadIdx.x;
  const int wave = tid >> 6;
  const int lane = tid & 63;
  const size_t rowoff = (size_t)blockIdx.x * NDIM;
  const float* xr   = x + rowoff;
  float*       outr = out + rowoff;

  { // zero LDS (covers k-padding; real values overwritten after barrier)
    int4 z; z.x = z.y = z.z = z.w = 0;
    int4* p = (int4*)Yt;
#pragma unroll
    for (int i = 0; i < 8; ++i) p[tid + i * 256] = z;
  }
  __syncthreads();

  // ---------------- Stage 1: FHT-64 per segment, fp32, on-load ----------------
  const int grp = tid >> 3;  // 0..31  (segment within pass)
  const int lid = tid & 7;   // lane within 8-lane segment group
  const float scale = 1.0f / sqrtf(11008.0f);

#pragma unroll
  for (int p = 0; p < 6; ++p) {
    const int k = p * 32 + grp;
    if (k < KREM) {
      const float4* seg = (const float4*)(xr + k * 64 + lid * 8);
      float4 a = seg[0], b = seg[1];
      float v[8] = {a.x, a.y, a.z, a.w, b.x, b.y, b.z, b.w};
      // in-register butterfly stages (m-strides 1,2,4)
#pragma unroll
      for (int s = 1; s <= 4; s <<= 1) {
#pragma unroll
        for (int i = 0; i < 8; ++i) {
          if ((i & s) == 0) {
            float u0 = v[i], u1 = v[i + s];
            v[i] = u0 + u1;
            v[i + s] = u0 - u1;
          }
        }
      }
      // cross-lane stages (m-strides 8,16,32 -> lane masks 1,2,4)
#pragma unroll
      for (int s = 1; s <= 4; s <<= 1) {
        const bool hi = (lid & s) != 0;
#pragma unroll
        for (int i = 0; i < 8; ++i) {
          float t = __shfl_xor(v[i], s, 64);
          v[i] = hi ? (t - v[i]) : (v[i] + t);
        }
      }
      // write transposed + swizzled bf16
      const int kb = k >> 3, ko = k & 7;
      const int kbs = (kb ^ lid) << 3;   // n>>3 == lid
#pragma unroll
      for (int i = 0; i < 8; ++i) {
        const int n = lid * 8 + i;
        Yt[n * KP_Y + kbs + ko] = f2bf(v[i] * scale);
      }
    }
  }
  __syncthreads();

  // ---------------- Stage 2: Z^T = Y^T(64x192) @ had^T(192x176) via MFMA ------
  const int l15 = lane & 15;
  const int q   = lane >> 4;
  const int njt = (wave < 3) ? 3 : 2;  // waves own jt = {w, w+4, w+8} (<11)

  f32x4 acc[3][4] = {};  // [j-tile local][n-tile]

#pragma unroll
  for (int kc = 0; kc < 6; ++kc) {
    const int kbase = kc * 32 + q * 8;
    bf16x8 afr[4];
#pragma unroll
    for (int nt = 0; nt < 4; ++nt) {
      const int n  = nt * 16 + l15;
      const int kb = (kbase >> 3) ^ (n >> 3);
      afr[nt] = *(const bf16x8*)&Yt[n * KP_Y + (kb << 3)];
    }
#pragma unroll
    for (int jl = 0; jl < 3; ++jl) {
      if (jl < njt) {
        const int jt = wave + jl * 4;
        const bf16x8 bfr =
            *(const bf16x8*)&hadB[(jt * 16 + l15) * KP_HAD + kbase];
#pragma unroll
        for (int nt = 0; nt < 4; ++nt)
          acc[jl][nt] = __builtin_amdgcn_mfma_f32_16x16x32_bf16(
              afr[nt], bfr, acc[jl][nt], 0, 0, 0);
      }
    }
  }

  // epilogue: D[row=n=q*4+reg][col=j=l15] -> out[j*64 + n], contiguous float4
#pragma unroll
  for (int jl = 0; jl < 3; ++jl) {
    if (jl < njt) {
      const int j = (wave + jl * 4) * 16 + l15;
      if (j < KREM) {
#pragma unroll
        for (int nt = 0; nt < 4; ++nt) {
          *(f32x4*)(outr + j * 64 + nt * 16 + q * 4) = acc[jl][nt];
        }
      }
    }
  }
}

extern "C" void kernel_launch(void* const* d_in, const int* in_sizes, int n_in,
                              void* d_out, int out_size, void* d_ws, size_t ws_size,
                              hipStream_t stream) {
  const float* x   = (const float*)d_in[0];
  const float* had = (const float*)d_in[1];
  unsigned short* hadB = (unsigned short*)d_ws;   // 176*192*2 = 67584 B
  float* out = (float*)d_out;
  const int rows = in_sizes[0] / NDIM;            // 8192

  hipLaunchKernelGGL(prep_had_kernel, dim3((JPAD * KP_HAD + 255) / 256),
                     dim3(256), 0, stream, had, hadB);
  hipLaunchKernelGGL(had_fused_kernel, dim3(rows), dim3(256), 0, stream,
                     x, hadB, out);
}